// Round 2
// baseline (182295.911 us; speedup 1.0000x reference)
//
#include <hip/hip_runtime.h>
#include <hip/hip_bf16.h>

#define NT   262144
#define FDIM 32
#define SDIM 32
#define HDIM 64
#define EPSV 1e-12f

// ---------------------------------------------------------------------------
// Kernel 1: parallel precompute of the v-independent linear terms.
//   gl[t*S+i] = sum_j X[t*F+j] * gate_beta[j*S+i]   -> stored into out_z region
//   rl[t*S+i] = sum_j X[t*F+j] * reset_gamma[j*S+i] -> stored into out_cand region
// The scan kernel reads these and overwrites them with z / cand in place.
// ---------------------------------------------------------------------------
__global__ void precompute_lin(const float* __restrict__ X,
                               const float* __restrict__ gb,
                               const float* __restrict__ rg,
                               float* __restrict__ gl,
                               float* __restrict__ rl)
{
    int idx = blockIdx.x * blockDim.x + threadIdx.x;   // = t*32 + i
    int t = idx >> 5;
    int i = idx & 31;
    const float* xr = X + (size_t)t * FDIM;
    float a = 0.f, b = 0.f;
#pragma unroll
    for (int j = 0; j < FDIM; ++j) {
        float xv = xr[j];
        a = fmaf(xv, gb[j * SDIM + i], a);
        b = fmaf(xv, rg[j * SDIM + i], b);
    }
    gl[idx] = a;
    rl[idx] = b;
}

// ---------------------------------------------------------------------------
// Fast device math (accuracy ~2ulp; recurrence is contracting so drift is
// bounded; threshold is 2.1e-2).
// ---------------------------------------------------------------------------
__device__ __forceinline__ float sigmoid_f(float x) {
    return 1.f / (1.f + __expf(-x));
}
__device__ __forceinline__ float tanh_f(float x) {
    // 1 - 2/(e^{2x}+1); saturates correctly at +-1 for large |x|
    float e = __expf(2.f * x);
    return 1.f - 2.f / (e + 1.f);
}
__device__ __forceinline__ float softplus_f(float x) {
    // stable: max(x,0) + log1p(exp(-|x|)); log1p ~ log(1+e) is fine here
    return fmaxf(x, 0.f) + __logf(1.f + __expf(-fabsf(x)));
}

// ---------------------------------------------------------------------------
// Kernel 2: the sequential scan. ONE wave (64 lanes).
//   lane l (l=0..63): owns W1 row l (h[l]); lanes mirrored mod 32 own state i.
//   matvec2 split: lane l computes half-dot of W2 row (l&31) over h-cols
//   (l>>5)*32..+31, combined with shfl_xor(32).
// All cross-lane traffic is wave-synchronous LDS (no s_barrier / no vmcnt
// drain, so global prefetch loads stay in flight across steps).
// ---------------------------------------------------------------------------
__global__ void __launch_bounds__(64, 1)
scan_kernel(const float* __restrict__ returns,
            const float* __restrict__ gsw,      // gate_state_weight [S]
            const float* __restrict__ rsw,      // reset_state_weight [S]
            const float* __restrict__ W1,       // [H, 3+S] row-major
            const float* __restrict__ b1,       // [H]
            const float* __restrict__ W2,       // [S, H] row-major
            const float* __restrict__ b2,       // [S]
            float* __restrict__ out_sigma,      // [N]
            float* __restrict__ out_z,          // [N*S]  (pre-filled with gl)
            float* __restrict__ out_cand,       // [N*S]  (pre-filled with rl)
            float* __restrict__ out_vfinal)     // [S]
{
    const int lane = threadIdx.x;        // 0..63
    const int i    = lane & 31;          // state index (mirrored halves)
    const int half = lane >> 5;          // 0 or 1

    __shared__ __align__(16) float smA[64];   // rv broadcast
    __shared__ __align__(16) float smB[64];   // h broadcast

    // ---- static weights into registers ----
    const float gswi = gsw[i];
    const float rswi = rsw[i];
    float w1r[35];
#pragma unroll
    for (int j = 0; j < 35; ++j) w1r[j] = W1[lane * 35 + j];
    const float b1l = b1[lane];
    float w2r[32];
#pragma unroll
    for (int j = 0; j < 32; ++j) w2r[j] = W2[i * HDIM + (half << 5) + j];
    const float b2i = b2[i];

    // ---- initial state ----
    const float r0 = returns[0];
    float v = r0 * r0;

    // ---- 2-deep prefetch buffers ----
    float glA = out_z[i];
    float rlA = out_cand[i];
    float rA  = r0;
    float glB = out_z[SDIM + i];
    float rlB = out_cand[SDIM + i];
    float rB  = returns[1];

    auto STEP = [&](int t, float gl, float rl, float r) {
        // gates (parallel over state i, mirrored in both halves)
        float z     = sigmoid_f(fmaf(gswi, v, gl));
        float reset = sigmoid_f(fmaf(rswi, v, rl));
        float rv    = reset * v;

        // broadcast rv via LDS (wave-synchronous)
        smA[lane] = rv;
        __builtin_amdgcn_wave_barrier();

        // h[lane] = b1 + W1[lane,:] . [r, |r|, r^2, rv]
        float h = b1l;
        h = fmaf(w1r[0], r, h);
        h = fmaf(w1r[1], fabsf(r), h);
        h = fmaf(w1r[2], r * r, h);
        const float4* rvp = (const float4*)smA;
#pragma unroll
        for (int q = 0; q < 8; ++q) {
            float4 x4 = rvp[q];
            h = fmaf(w1r[3 + 4 * q + 0], x4.x, h);
            h = fmaf(w1r[3 + 4 * q + 1], x4.y, h);
            h = fmaf(w1r[3 + 4 * q + 2], x4.z, h);
            h = fmaf(w1r[3 + 4 * q + 3], x4.w, h);
        }
        float th = tanh_f(h);

        // broadcast h via LDS
        smB[lane] = th;
        __builtin_amdgcn_wave_barrier();

        // raw[i] = b2 + W2[i,:] . h   (half-dot per lane, combine across halves)
        float p = 0.f;
        const float4* hp = (const float4*)(smB + (half << 5));
#pragma unroll
        for (int q = 0; q < 8; ++q) {
            float4 h4 = hp[q];
            p = fmaf(w2r[4 * q + 0], h4.x, p);
            p = fmaf(w2r[4 * q + 1], h4.y, p);
            p = fmaf(w2r[4 * q + 2], h4.z, p);
            p = fmaf(w2r[4 * q + 3], h4.w, p);
        }
        p += __shfl_xor(p, 32);
        float raw  = p + b2i;
        float cand = softplus_f(raw);

        float vn = fmaxf(fmaf(z, cand - v, v), EPSV);

        // outputs (z/cand overwrite the gl/rl slots of this t)
        if (lane < SDIM) {
            out_z  [(size_t)t * SDIM + i] = z;
            out_cand[(size_t)t * SDIM + i] = cand;
        }
        // sigma2[t] = mean(v_next) over 32 states (reduce within 32-group)
        float s = vn;
        s += __shfl_xor(s, 1);
        s += __shfl_xor(s, 2);
        s += __shfl_xor(s, 4);
        s += __shfl_xor(s, 8);
        s += __shfl_xor(s, 16);
        if (lane == 0) out_sigma[t] = s * (1.f / 32.f);

        v = vn;
        __builtin_amdgcn_wave_barrier();   // keep LDS reuse ordered across steps
    };

    for (int t = 0; t < NT; t += 2) {
        // prefetch t+2 (clamped at tail; clamped loads are discarded)
        int t2 = (t + 2 < NT) ? (t + 2) : t;
        float glA2 = out_z  [(size_t)t2 * SDIM + i];
        float rlA2 = out_cand[(size_t)t2 * SDIM + i];
        float rA2  = returns[t2];

        STEP(t, glA, rlA, rA);

        int t3 = (t + 3 < NT) ? (t + 3) : t;
        float glB2 = out_z  [(size_t)t3 * SDIM + i];
        float rlB2 = out_cand[(size_t)t3 * SDIM + i];
        float rB2  = returns[t3];

        STEP(t + 1, glB, rlB, rB);

        glA = glA2; rlA = rlA2; rA = rA2;
        glB = glB2; rlB = rlB2; rB = rB2;
    }

    if (lane < SDIM) out_vfinal[i] = v;
}

// ---------------------------------------------------------------------------
extern "C" void kernel_launch(void* const* d_in, const int* in_sizes, int n_in,
                              void* d_out, int out_size, void* d_ws, size_t ws_size,
                              hipStream_t stream)
{
    const float* X          = (const float*)d_in[0];
    const float* returns    = (const float*)d_in[1];
    const float* gate_beta  = (const float*)d_in[2];
    const float* gsw        = (const float*)d_in[3];
    const float* reset_gamma= (const float*)d_in[4];
    const float* rsw        = (const float*)d_in[5];
    const float* W1         = (const float*)d_in[6];
    const float* b1         = (const float*)d_in[7];
    const float* W2         = (const float*)d_in[8];
    const float* b2         = (const float*)d_in[9];

    float* out       = (float*)d_out;
    float* out_sigma = out;                                   // [N]
    float* out_z     = out + NT;                              // [N*S]
    float* out_cand  = out + NT + (size_t)NT * SDIM;          // [N*S]
    float* out_vfin  = out + NT + 2 * (size_t)NT * SDIM;      // [S]

    // gl -> out_z region, rl -> out_cand region (scan overwrites in place)
    precompute_lin<<<(NT * SDIM) / 256, 256, 0, stream>>>(
        X, gate_beta, reset_gamma, out_z, out_cand);

    scan_kernel<<<1, 64, 0, stream>>>(
        returns, gsw, rsw, W1, b1, W2, b2,
        out_sigma, out_z, out_cand, out_vfin);
}

// Round 3
// 1098.189 us; speedup vs baseline: 165.9969x; 165.9969x over previous
//
#include <hip/hip_runtime.h>

#define NT    262144
#define SDIM  32
#define NSEG  256            // parallel speculative segments (1 block = 1 wave each)
#define SEG   (NT / NSEG)    // 1024 steps per segment
#define WARM  512            // warm-up steps (contraction kills the v-guess error)
#define EPSV  1e-12f
#define L2E   1.4426950408889634f   // log2(e)
#define LN2   0.6931471805599453f

// ---------------------------------------------------------------------------
// Kernel 1: parallel precompute of v-independent gate terms, PRE-SCALED for
// exp2-native sigmoids:  glN = -log2(e)*(X@gate_beta), rlN likewise.
// Stored into the out_z / out_cand regions; the scan reads its own segment
// then overwrites in place with z / cand.
// ---------------------------------------------------------------------------
__global__ void precompute_lin(const float* __restrict__ X,
                               const float* __restrict__ gb,
                               const float* __restrict__ rg,
                               float* __restrict__ glN,
                               float* __restrict__ rlN)
{
    int idx = blockIdx.x * blockDim.x + threadIdx.x;   // = t*32 + i
    int t = idx >> 5, i = idx & 31;
    const float* xr = X + (size_t)t * 32;
    float a = 0.f, b = 0.f;
#pragma unroll
    for (int j = 0; j < 32; ++j) {
        float xv = xr[j];
        a = fmaf(xv, gb[j * 32 + i], a);
        b = fmaf(xv, rg[j * 32 + i], b);
    }
    glN[idx] = -L2E * a;
    rlN[idx] = -L2E * b;
}

// full-wave (64) sum via DPP row_shr/bcast chain; total lands in lane 63.
__device__ __forceinline__ float wave_sum64(float x) {
    float s = x;
#define DPP_ADD(ctrl)                                                          \
    {   int t_ = __builtin_amdgcn_update_dpp(0, __builtin_bit_cast(int, s),    \
                                             (ctrl), 0xF, 0xF, true);          \
        s += __builtin_bit_cast(float, t_); }
    DPP_ADD(0x111)  // row_shr:1
    DPP_ADD(0x112)  // row_shr:2
    DPP_ADD(0x114)  // row_shr:4
    DPP_ADD(0x118)  // row_shr:8   -> lanes 15/31/47/63 hold row-of-16 sums
    DPP_ADD(0x142)  // row_bcast15 -> lane31=sum(0:32), lane63=sum(32:64)
    DPP_ADD(0x143)  // row_bcast31 -> lane63=sum(0:64)
#undef DPP_ADD
    return s;
}

// ---------------------------------------------------------------------------
// Kernel 2: speculative-parallel scan. NSEG independent blocks (1 wave each).
// Block b: warm-up [tstart-WARM, tstart) from v-guess (gl/rl recomputed from
// X -> no cross-segment reads -> race-free), then segment [tstart, tend)
// reading its own glN/rlN and overwriting with z/cand in place.
// Lane l: W1 row l (h_l); state i = l&31 mirrored in both halves.
// All cross-lane traffic is wave-synchronous LDS (in-order DS pipe).
// ---------------------------------------------------------------------------
__global__ void __launch_bounds__(64, 1)
scan_kernel(const float* __restrict__ returns,
            const float* __restrict__ gsw,
            const float* __restrict__ rsw,
            const float* __restrict__ W1,     // [64, 35]
            const float* __restrict__ b1,     // [64]
            const float* __restrict__ W2,     // [32, 64]
            const float* __restrict__ b2,     // [32]
            const float* __restrict__ X,      // [N, 32] (warm-up only)
            const float* __restrict__ gb,     // [32, 32] (warm-up only)
            const float* __restrict__ rg,     // [32, 32] (warm-up only)
            float* __restrict__ out_sigma,    // [N]
            float* __restrict__ out_z,        // [N*32]  (pre-filled glN)
            float* __restrict__ out_cand,     // [N*32]  (pre-filled rlN)
            float* __restrict__ out_vfinal)   // [32]
{
    const int lane = threadIdx.x;
    const int i    = lane & 31;
    const int bid  = blockIdx.x;
    const int tstart = bid * SEG;
    const int tend   = tstart + SEG;
    const int ws     = (bid == 0) ? 0 : (tstart - WARM);

    __shared__ __align__(16) float smA[64];   // rv broadcast
    __shared__ __align__(16) float smB[64];   // tanh(h) broadcast

    // ---- static weights, pre-scaled so every transcendental is exp2/log2 ----
    const float gswN = -L2E * gsw[i];
    const float rswN = -L2E * rsw[i];
    float w1r[35];                       // rows scaled by 2*log2(e) for tanh
#pragma unroll
    for (int j = 0; j < 35; ++j) w1r[j] = (2.f * L2E) * W1[lane * 35 + j];
    const float b1l = (2.f * L2E) * b1[lane];
    float w2r[64];                       // full W2 row, scaled by log2(e)
#pragma unroll
    for (int j = 0; j < 64; ++j) w2r[j] = L2E * W2[i * 64 + j];
    const float b2l = L2E * b2[i];

    // ---- initial state (block 0 exact; others: bounded guess, converges) ----
    float r00 = returns[(bid == 0) ? 0 : ws];
    float v = r00 * r00;

    // one step. glN/rlN are the pre-negated-scaled gate linear terms.
    auto STEP = [&](int t, float glN, float rlN, float r, bool dostore) {
        // gates: z = 1/(1+exp2(glN + gswN*v)), reset likewise
        float z  = __builtin_amdgcn_rcpf(
                       1.f + __builtin_amdgcn_exp2f(fmaf(gswN, v, glN)));
        float rs = __builtin_amdgcn_rcpf(
                       1.f + __builtin_amdgcn_exp2f(fmaf(rswN, v, rlN)));
        float rv = rs * v;

        smA[lane] = rv;
        __builtin_amdgcn_wave_barrier();

        // h' = 2*log2e*(W1.x + b1), 4-accumulator dot
        float h0 = b1l;
        h0 = fmaf(w1r[0], r, h0);
        h0 = fmaf(w1r[1], fabsf(r), h0);
        h0 = fmaf(w1r[2], r * r, h0);
        float h1 = 0.f, h2 = 0.f, h3 = 0.f;
        const float4* rvp = (const float4*)smA;
#pragma unroll
        for (int q = 0; q < 8; ++q) {
            float4 x4 = rvp[q];
            h0 = fmaf(w1r[3 + 4 * q + 0], x4.x, h0);
            h1 = fmaf(w1r[3 + 4 * q + 1], x4.y, h1);
            h2 = fmaf(w1r[3 + 4 * q + 2], x4.z, h2);
            h3 = fmaf(w1r[3 + 4 * q + 3], x4.w, h3);
        }
        float hp_ = (h0 + h1) + (h2 + h3);
        // tanh(x) = 1 - 2/(exp2(x') + 1)
        float th = fmaf(-2.f,
                        __builtin_amdgcn_rcpf(__builtin_amdgcn_exp2f(hp_) + 1.f),
                        1.f);

        smB[lane] = th;
        __builtin_amdgcn_wave_barrier();

        // raw' = log2e*(W2.th + b2): full 64-dot per lane, 8 accumulators
        float p0 = 0.f, p1 = 0.f, p2 = 0.f, p3 = 0.f;
        float p4 = 0.f, p5 = 0.f, p6 = 0.f, p7 = 0.f;
        const float4* hp = (const float4*)smB;
#pragma unroll
        for (int q = 0; q < 16; q += 2) {
            float4 a4 = hp[q];
            p0 = fmaf(w2r[4 * q + 0], a4.x, p0);
            p1 = fmaf(w2r[4 * q + 1], a4.y, p1);
            p2 = fmaf(w2r[4 * q + 2], a4.z, p2);
            p3 = fmaf(w2r[4 * q + 3], a4.w, p3);
            float4 b4 = hp[q + 1];
            p4 = fmaf(w2r[4 * q + 4], b4.x, p4);
            p5 = fmaf(w2r[4 * q + 5], b4.y, p5);
            p6 = fmaf(w2r[4 * q + 6], b4.z, p6);
            p7 = fmaf(w2r[4 * q + 7], b4.w, p7);
        }
        float rawp = (((p0 + p4) + (p1 + p5)) + ((p2 + p6) + (p3 + p7))) + b2l;
        // softplus(raw) = ln2 * (max(raw',0) + log2(1 + exp2(-|raw'|)))
        float e  = __builtin_amdgcn_exp2f(-fabsf(rawp));
        float sp = fmaxf(rawp, 0.f) + __builtin_amdgcn_logf(1.f + e);
        float cand = LN2 * sp;

        float vn = fmaxf(fmaf(z, cand - v, v), EPSV);

        if (dostore) {
            // mirrored halves write identical values to identical addresses
            out_z  [(size_t)t * SDIM + i] = z;
            out_cand[(size_t)t * SDIM + i] = cand;
            float s = wave_sum64(vn);          // VALU DPP chain, off the v-path
            if (lane == 63) out_sigma[t] = s * (1.f / 64.f);
        }
        v = vn;
    };

    // ---- warm-up: gl/rl recomputed from X (no cross-segment out_z reads) ----
    if (bid != 0) {
        float gbN[32], rgN[32];           // -log2e * beta columns for state i
#pragma unroll
        for (int j = 0; j < 32; ++j) {
            gbN[j] = -L2E * gb[j * 32 + i];
            rgN[j] = -L2E * rg[j * 32 + i];
        }
        // prefetch first X row + r
        float4 xb[8];
        {
            const float4* xr = (const float4*)(X + (size_t)ws * 32);
#pragma unroll
            for (int q = 0; q < 8; ++q) xb[q] = xr[q];
        }
        float rc = returns[ws];

        for (int t = ws; t < tstart; ++t) {
            int tn = (t + 1 < tstart) ? (t + 1) : t;
            float4 xn[8];
            const float4* xr = (const float4*)(X + (size_t)tn * 32);
#pragma unroll
            for (int q = 0; q < 8; ++q) xn[q] = xr[q];
            float rn = returns[tn];

            // glN/rlN = sum_j xb_j * betaN[j], 4 accumulators each
            float a0 = 0.f, a1 = 0.f, a2 = 0.f, a3 = 0.f;
            float c0 = 0.f, c1 = 0.f, c2 = 0.f, c3 = 0.f;
#pragma unroll
            for (int q = 0; q < 8; ++q) {
                float4 x4 = xb[q];
                a0 = fmaf(gbN[4 * q + 0], x4.x, a0);
                a1 = fmaf(gbN[4 * q + 1], x4.y, a1);
                a2 = fmaf(gbN[4 * q + 2], x4.z, a2);
                a3 = fmaf(gbN[4 * q + 3], x4.w, a3);
                c0 = fmaf(rgN[4 * q + 0], x4.x, c0);
                c1 = fmaf(rgN[4 * q + 1], x4.y, c1);
                c2 = fmaf(rgN[4 * q + 2], x4.z, c2);
                c3 = fmaf(rgN[4 * q + 3], x4.w, c3);
            }
            STEP(t, (a0 + a1) + (a2 + a3), (c0 + c1) + (c2 + c3), rc, false);
#pragma unroll
            for (int q = 0; q < 8; ++q) xb[q] = xn[q];
            rc = rn;
        }
    }

    // ---- segment: read own glN/rlN (prefetch clamped to OWN range), store ----
    float glA = out_z  [(size_t)tstart * SDIM + i];
    float rlA = out_cand[(size_t)tstart * SDIM + i];
    float rA  = returns[tstart];
    float glB = out_z  [(size_t)(tstart + 1) * SDIM + i];
    float rlB = out_cand[(size_t)(tstart + 1) * SDIM + i];
    float rB  = returns[tstart + 1];

    for (int t = tstart; t < tend; t += 2) {
        int t2 = (t + 2 < tend) ? (t + 2) : (tend - 1);   // clamp INSIDE segment
        float glA2 = out_z  [(size_t)t2 * SDIM + i];
        float rlA2 = out_cand[(size_t)t2 * SDIM + i];
        float rA2  = returns[t2];

        STEP(t, glA, rlA, rA, true);

        int t3 = (t + 3 < tend) ? (t + 3) : (tend - 1);
        float glB2 = out_z  [(size_t)t3 * SDIM + i];
        float rlB2 = out_cand[(size_t)t3 * SDIM + i];
        float rB2  = returns[t3];

        STEP(t + 1, glB, rlB, rB, true);

        glA = glA2; rlA = rlA2; rA = rA2;
        glB = glB2; rlB = rlB2; rB = rB2;
    }

    if (bid == NSEG - 1 && lane < SDIM) out_vfinal[i] = v;
}

// ---------------------------------------------------------------------------
extern "C" void kernel_launch(void* const* d_in, const int* in_sizes, int n_in,
                              void* d_out, int out_size, void* d_ws, size_t ws_size,
                              hipStream_t stream)
{
    const float* X          = (const float*)d_in[0];
    const float* returns    = (const float*)d_in[1];
    const float* gate_beta  = (const float*)d_in[2];
    const float* gsw        = (const float*)d_in[3];
    const float* reset_gamma= (const float*)d_in[4];
    const float* rsw        = (const float*)d_in[5];
    const float* W1         = (const float*)d_in[6];
    const float* b1         = (const float*)d_in[7];
    const float* W2         = (const float*)d_in[8];
    const float* b2         = (const float*)d_in[9];

    float* out       = (float*)d_out;
    float* out_sigma = out;                                   // [N]
    float* out_z     = out + NT;                              // [N*S]
    float* out_cand  = out + NT + (size_t)NT * SDIM;          // [N*S]
    float* out_vfin  = out + NT + 2 * (size_t)NT * SDIM;      // [S]

    precompute_lin<<<(NT * SDIM) / 256, 256, 0, stream>>>(
        X, gate_beta, reset_gamma, out_z, out_cand);

    scan_kernel<<<NSEG, 64, 0, stream>>>(
        returns, gsw, rsw, W1, b1, W2, b2,
        X, gate_beta, reset_gamma,
        out_sigma, out_z, out_cand, out_vfin);
}